// Round 16
// baseline (222.585 us; speedup 1.0000x reference)
//
#include <hip/hip_runtime.h>
#include <hip/hip_bf16.h>
#include <math.h>

// ISTFT as a single atomic-free bf16 GEMM over an overlapped row view.
//   out[b][r*256+j] = A_view[b,r] (contiguous 4160 bf16, row stride 1040)
//                     dot Bstack[4160][256]   (see R13 header for derivation)
// R16: barrier-free 1-wave-per-block GEMM with counted-vmcnt double buffer.
//   R15's 2-barrier 128x64 structure: 8 MFMA per 6 ds_read per 2 barriers per
//   vmcnt(0) drain -> MfmaUtil 16%. Here: 64-thread blocks, wave-private LDS
//   (2 x 8 KB double buffer) -> NO __syncthreads; 2-deep global_load_lds
//   prefetch with s_waitcnt vmcnt(8) (counted, never 0 mid-loop, T4);
//   per-wave 64x64 tile = 16 MFMA / 8 ds_read per K-step (m97 ratio).
//   Grid 528 M-tiles x 4 N = 2112 blocks (~8 waves/CU); XCD remap (528 = 8*66)
//   keeps each A-panel's 4 sharers concurrent on one XCD's L2.

#define BATCH  16
#define TFR    2048
#define NB     513
#define HOP    256
#define OUTLEN 525056
#define RROWS  2051                   // output rows per batch (525056/256)
#define PBR    2054                   // padded rows per batch: 3 + 2048 + 3
#define FSTR   1040                   // bf16 elems per padded frame row
#define KTOT   (4 * FSTR)             // 4160
#define BK     32
#define NKT    (KTOT / BK)            // 130
#define KVAL   1026                   // valid elems per frame row
#define MTB    33                     // M-tiles (64-row) per batch: 33*64 = 2112 >= 2051
#define MTOT   (BATCH * MTB)          // 528 = 8 XCDs * 66
#define TOTROW (BATCH * PBR + 128)    // 32992 incl. slack rows (OOB-read guard)
#define CHPR   (FSTR / 8)             // 130 8-elem chunks per row

typedef __attribute__((ext_vector_type(4))) float f32x4;
typedef __attribute__((ext_vector_type(8))) short bf16x8;

__device__ __forceinline__ void load_lds16(const void* g, void* l)
{
    __builtin_amdgcn_global_load_lds((const __attribute__((address_space(1))) void*)g,
                                     (__attribute__((address_space(3))) void*)l,
                                     16, 0, 0);
}

#define STEP 6.13592315e-3f           // 2*pi/1024

// ---- Bstack, stored transposed: Bg[j][k], k contiguous (row stride KTOT) ----
__global__ __launch_bounds__(256)
void build_B(__hip_bfloat16* __restrict__ Bg)
{
    __shared__ float cosT[1024];
    __shared__ float sinT[1024];
    const int j = blockIdx.x;
    for (int i = threadIdx.x; i < 1024; i += 256) {
        float s, c;
        sincosf((float)i * STEP, &s, &c);
        cosT[i] = c; sinT[i] = s;
    }
    __syncthreads();

    for (int k = threadIdx.x; k < KTOT; k += 256) {
        const int d  = k / FSTR;
        const int kk = k - d * FSTR;
        float val = 0.f;
        if (kk < KVAL) {
            const int   f   = kk >> 1;
            const int   n   = 768 - 256 * d + j;              // 0..1023
            const float syn = (0.5f - 0.5f * cosT[n]) * 0.8660254f * (1.0f / 1024.0f);
            const int   idx = (n * f) & 1023;
            if ((kk & 1) == 0) {
                const float wr = (f == 0 || f == 512) ? 1.f : 2.f;
                val = wr * cosT[idx] * syn;
            } else {
                val = -2.f * sinT[idx] * syn;
            }
        }
        Bg[(size_t)j * KTOT + k] = __float2bfloat16(val);
    }
}

// ---- convert: stfts fp32 -> Ab bf16 padded layout (see R13) ----
__global__ __launch_bounds__(256)
void convert_A(const float* __restrict__ A, __hip_bfloat16* __restrict__ Ab)
{
    const int idx = blockIdx.x * 256 + threadIdx.x;
    if (idx >= TOTROW * CHPR) return;
    const int row = idx / CHPR;
    const int c8  = (idx - row * CHPR) * 8;

    const int b  = row / PBR;                 // >=16 -> slack
    const int rr = row - b * PBR;
    const bool valid = (b < BATCH) && (rr >= 3) && (rr < 3 + TFR);

    union { bf16x8 v; __hip_bfloat162 h[4]; } u;
    if (valid) {
        const int t = rr - 3;
        const float* src = A + (size_t)(b * TFR + t) * KVAL + c8;
        #pragma unroll
        for (int j = 0; j < 8; j += 2) {
            float2 p = make_float2(0.f, 0.f);
            if (c8 + j < KVAL)                // KVAL even: pair all-or-nothing
                p = *reinterpret_cast<const float2*>(src + j);
            u.h[j >> 1] = __float22bfloat162_rn(p);
        }
    } else {
        #pragma unroll
        for (int j = 0; j < 4; ++j) u.h[j] = __float22bfloat162_rn(make_float2(0.f, 0.f));
    }
    *reinterpret_cast<bf16x8*>(Ab + (size_t)row * FSTR + c8) = u.v;
}

// ---- GEMM: 1 wave/block, 64x64 tile, barrier-free counted-vmcnt pipeline ----
__global__ __launch_bounds__(64)
void istft_gemm5(const __hip_bfloat16* __restrict__ Ab,
                 const __hip_bfloat16* __restrict__ Bg,
                 float* __restrict__ out)
{
    __shared__ __hip_bfloat16 Asl[2][64 * BK];   // 2 x 4 KB
    __shared__ __hip_bfloat16 Bsl[2][64 * BK];   // 2 x 4 KB

    const int lane = threadIdx.x;                // 0..63

    // XCD-aware remap: 2112 blocks = 8 XCDs x (66 M-tiles x 4 N-tiles)
    const int wg   = blockIdx.x;
    const int xcd  = wg & 7;
    const int slot = wg >> 3;                    // 0..263
    const int mtg  = xcd * 66 + (slot >> 2);     // 0..527
    const int nt   = slot & 3;

    const int b  = mtg / MTB;
    const int rt = (mtg - b * MTB) * 64;
    const int n0 = nt * 64;

    // staging map: pass i covers rows i*16 + lane/4, col (lane&3)*8
    const int srow = lane >> 2;
    const int scol = (lane & 3) * 8;
    const __hip_bfloat16* gA = Ab + ((size_t)b * PBR + rt + srow) * FSTR + scol;
    const __hip_bfloat16* gB = Bg + (size_t)(n0 + srow) * KTOT + scol;

    // frag map
    const int fr = lane & 15;
    const int fk = (lane >> 4) * 8;

    f32x4 acc[4][4] = {};

#define STAGE(buf, kt)                                                          \
    {                                                                           \
        const int _ko = (kt) * BK;                                              \
        _Pragma("unroll")                                                       \
        for (int _i = 0; _i < 4; ++_i) {                                        \
            load_lds16(gA + (size_t)_i * 16 * FSTR + _ko,                       \
                       &Asl[buf][_i * 512 + lane * 8]);                         \
            load_lds16(gB + (size_t)_i * 16 * KTOT + _ko,                       \
                       &Bsl[buf][_i * 512 + lane * 8]);                         \
        }                                                                       \
    }

    STAGE(0, 0)
    STAGE(1, 1)

    for (int kt = 0; kt < NKT; ++kt) {
        // counted wait: oldest 8 (this kt's buffer) complete; newest 8 in flight
        if (kt + 1 < NKT) { asm volatile("s_waitcnt vmcnt(8)" ::: "memory"); }
        else              { asm volatile("s_waitcnt vmcnt(0)" ::: "memory"); }
        __builtin_amdgcn_sched_barrier(0);

        const int buf = kt & 1;
        bf16x8 a[4], bv[4];
        #pragma unroll
        for (int mi = 0; mi < 4; ++mi)
            a[mi] = *reinterpret_cast<const bf16x8*>(&Asl[buf][(mi * 16 + fr) * BK + fk]);
        #pragma unroll
        for (int ni = 0; ni < 4; ++ni)
            bv[ni] = *reinterpret_cast<const bf16x8*>(&Bsl[buf][(ni * 16 + fr) * BK + fk]);

        // frags now requested; drain DS before re-staging this buffer (hazard fence)
        asm volatile("s_waitcnt lgkmcnt(0)" ::: "memory");
        __builtin_amdgcn_sched_barrier(0);

        if (kt + 2 < NKT) STAGE(buf, kt + 2)     // overwrites buf: reads done above

        #pragma unroll
        for (int mi = 0; mi < 4; ++mi)
            #pragma unroll
            for (int ni = 0; ni < 4; ++ni)
                acc[mi][ni] = __builtin_amdgcn_mfma_f32_16x16x32_bf16(
                    a[mi], bv[ni], acc[mi][ni], 0, 0, 0);
    }
#undef STAGE

    // epilogue: C/D layout col = lane&15, row = (lane>>4)*4 + j; plain stores
    const int cr = (lane >> 4) * 4;
    const int cc = lane & 15;
    #pragma unroll
    for (int mi = 0; mi < 4; ++mi) {
        #pragma unroll
        for (int ni = 0; ni < 4; ++ni) {
            const int col = n0 + ni * 16 + cc;
            #pragma unroll
            for (int j = 0; j < 4; ++j) {
                const int r = rt + mi * 16 + cr + j;
                if (r < RROWS)
                    out[(size_t)b * OUTLEN + (size_t)r * 256 + col] = acc[mi][ni][j];
            }
        }
    }
}

extern "C" void kernel_launch(void* const* d_in, const int* in_sizes, int n_in,
                              void* d_out, int out_size, void* d_ws, size_t ws_size,
                              hipStream_t stream)
{
    const float* A = reinterpret_cast<const float*>(d_in[0]);
    float* out = reinterpret_cast<float*>(d_out);

    const size_t abBytes = (size_t)TOTROW * FSTR * sizeof(__hip_bfloat16); // 68.62 MB
    __hip_bfloat16* Ab = reinterpret_cast<__hip_bfloat16*>(d_ws);
    __hip_bfloat16* Bg = reinterpret_cast<__hip_bfloat16*>((char*)d_ws + abBytes); // +2.13 MB

    build_B<<<dim3(256), dim3(256), 0, stream>>>(Bg);

    const int nChunks = TOTROW * CHPR;                       // 4,288,960
    convert_A<<<dim3((nChunks + 255) / 256), dim3(256), 0, stream>>>(A, Ab);

    istft_gemm5<<<dim3(MTOT * 4), dim3(64), 0, stream>>>(Ab, Bg, out);
}